// Round 1
// 1161.183 us; speedup vs baseline: 1.1776x; 1.1776x over previous
//
#include <hip/hip_runtime.h>
#include <hip/hip_bf16.h>

#define DE 100
#define RK 40
#define NENT 10000
#define BATCH 128
#define KDIM 1600          // 40*40
#define MN 10000           // 100*100
#define PRED_SIZE (BATCH*NENT)

typedef __bf16 bf16x8 __attribute__((ext_vector_type(8)));
typedef float floatx4 __attribute__((ext_vector_type(4)));

// RTNE float -> bf16 bits (manual, avoids header API differences)
static __device__ __forceinline__ unsigned short f2bf(float f) {
    unsigned int u = __builtin_bit_cast(unsigned int, f);
    unsigned int lsb = (u >> 16) & 1u;
    u += 0x7fffu + lsb;
    return (unsigned short)(u >> 16);
}

// ---------------- prep_A: A'[m=(i,j)][e=(a*40+c)] = sum_b f0[a,i,b] f1[b,j,c] ----------------
__global__ void prep_A_kernel(const float* __restrict__ f0, const float* __restrict__ f1,
                              unsigned short* __restrict__ Abf) {
    const int m = blockIdx.x;          // i*100 + j
    const int i = m / 100, j = m % 100;
    const int t = threadIdx.x;
    __shared__ __align__(16) float P[KDIM];  // F0[a*40+b]
    __shared__ __align__(16) float Q[KDIM];  // F1[b*40+c]
    for (int e = t; e < KDIM; e += 256) {
        const int u = e / 40, v = e % 40;
        P[e] = f0[u*4000 + i*40 + v];
        Q[e] = f1[u*4000 + j*40 + v];
    }
    __syncthreads();
    for (int o = t; o < 400; o += 256) {
        const int x  = o / 10;          // a
        const int z4 = (o % 10) * 4;    // c base
        float a0=0.f, a1=0.f, a2=0.f, a3=0.f;
        #pragma unroll
        for (int y = 0; y < 40; ++y) {
            const float s = P[x*40 + y];
            const float4 q = *reinterpret_cast<const float4*>(&Q[y*40 + z4]);
            a0 += s*q.x; a1 += s*q.y; a2 += s*q.z; a3 += s*q.w;
        }
        ushort4 r;
        r.x = f2bf(a0); r.y = f2bf(a1); r.z = f2bf(a2); r.w = f2bf(a3);
        *reinterpret_cast<ushort4*>(&Abf[(size_t)m*KDIM + x*40 + z4]) = r;
    }
}

// ---------------- prep_B: B'[n=(k,l)][e=(a*40+c)] = sum_d f2[c,k,d] f3[d,l,a] ----------------
__global__ void prep_B_kernel(const float* __restrict__ f2, const float* __restrict__ f3,
                              unsigned short* __restrict__ Bbf) {
    const int n = blockIdx.x;          // k*100 + l
    const int k = n / 100, l = n % 100;
    const int t = threadIdx.x;
    __shared__ __align__(16) float P[KDIM];   // F2[c*40+d]
    __shared__ __align__(16) float Q[KDIM];   // F3[d*40+a]
    __shared__ __align__(16) float Rt[KDIM];  // R[c*40+a]
    for (int e = t; e < KDIM; e += 256) {
        const int u = e / 40, v = e % 40;
        P[e] = f2[u*4000 + k*40 + v];
        Q[e] = f3[u*4000 + l*40 + v];
    }
    __syncthreads();
    for (int o = t; o < 400; o += 256) {
        const int x  = o / 10;          // c
        const int z4 = (o % 10) * 4;    // a base
        float a0=0.f, a1=0.f, a2=0.f, a3=0.f;
        #pragma unroll
        for (int y = 0; y < 40; ++y) {
            const float s = P[x*40 + y];
            const float4 q = *reinterpret_cast<const float4*>(&Q[y*40 + z4]);
            a0 += s*q.x; a1 += s*q.y; a2 += s*q.z; a3 += s*q.w;
        }
        Rt[x*40 + z4 + 0] = a0; Rt[x*40 + z4 + 1] = a1;
        Rt[x*40 + z4 + 2] = a2; Rt[x*40 + z4 + 3] = a3;
    }
    __syncthreads();
    // transpose-store: B'[n][a*40+c] = Rt[c*40+a]
    for (int o = t; o < 400; o += 256) {
        const int a  = o / 10;
        const int c4 = (o % 10) * 4;
        ushort4 r;
        r.x = f2bf(Rt[(c4+0)*40 + a]);
        r.y = f2bf(Rt[(c4+1)*40 + a]);
        r.z = f2bf(Rt[(c4+2)*40 + a]);
        r.w = f2bf(Rt[(c4+3)*40 + a]);
        *reinterpret_cast<ushort4*>(&Bbf[(size_t)n*KDIM + a*40 + c4]) = r;
    }
}

// ---------------- GEMM: W[m][n] = sum_e A'[m][e] * B'[n][e] ----------------
// 256x256 tile, BK=64, 8 waves (2M x 4N), double-buffered 128 KiB LDS,
// counted vmcnt (T4), XOR LDS swizzle via pre-swizzled global source (T2/rule 21),
// raw s_barrier (no vmcnt(0) drain), setprio around MFMA clusters (T5),
// bijective XCD swizzle (T1, 1600 % 8 == 0).
typedef __attribute__((address_space(1))) void gvoid;
typedef __attribute__((address_space(3))) void lvoid;
static __device__ __forceinline__ void async_cp16(const void* g, void* l) {
    gvoid* gp = (gvoid*)(unsigned long long)g;
    lvoid* lp = (lvoid*)(unsigned int)(unsigned long long)l;
    __builtin_amdgcn_global_load_lds(gp, lp, 16, 0, 0);
}

#define NKT 25            // 1600 / 64 K-tiles
#define LDS_TILE 16384    // ushorts per 256x64 tile (32 KB)

__global__ __launch_bounds__(512, 2) void gemm_kernel(const unsigned short* __restrict__ A,
                                                      const unsigned short* __restrict__ Bm,
                                                      float* __restrict__ W) {
    extern __shared__ unsigned short lds[];   // [2 bufs][A 16384 | B 16384] = 128 KiB
    const int t = threadIdx.x;
    const int w = t >> 6, l = t & 63;
    const int wm = w >> 2, wn = w & 3;        // 2 x 4 wave grid
    const int quad = l >> 4, lrow = l & 15;
    const int swz = lrow & 7;                 // LDS read-side XOR key (row & 7 == lrow & 7)

    // XCD-aware bijective swizzle: 1600 blocks, 8 XCDs, 200 per XCD
    const int orig = blockIdx.x;
    const int sb = (orig & 7) * 200 + (orig >> 3);
    const int by = sb / 40, bx = sb % 40;
    const int m0 = by * 256, n0 = bx * 256;

    // ---- staging addressing (global source pre-swizzled; LDS dest linear) ----
    // thread t stages rows {i*64 + (t>>3)}, LDS chunk t&7; source chunk (t&7)^(row&7)
    const int srow = t >> 3;                       // 0..63
    const int schk = (t & 7) ^ (srow & 7);         // swizzled source 16B-chunk
    int offA[4], offB[4];
    #pragma unroll
    for (int i = 0; i < 4; ++i) {
        int ra = m0 + i*64 + srow; if (ra > MN-1) ra = MN-1;
        int rb = n0 + i*64 + srow; if (rb > MN-1) rb = MN-1;
        offA[i] = ra * KDIM + schk * 8;
        offB[i] = rb * KDIM + schk * 8;
    }
    const int lds_off = t * 8;                     // ushort offset (16 B per thread)

    floatx4 acc[8][4] = {};

    // ---- prologue: stage tile 0 into buf0 ----
    #pragma unroll
    for (int i = 0; i < 4; ++i) {
        async_cp16(A  + offA[i], lds + i*4096 + lds_off);
        async_cp16(Bm + offB[i], lds + LDS_TILE + i*4096 + lds_off);
    }

    for (int kt = 0; kt < NKT; ++kt) {
        const int cur = kt & 1;
        const unsigned short* As = lds + cur * (2*LDS_TILE);
        const unsigned short* Bs = As + LDS_TILE;

        if (kt < NKT-1) {
            // issue next tile's stage into the other buffer (one full tile of lead)
            unsigned short* An = lds + (cur ^ 1) * (2*LDS_TILE);
            unsigned short* Bn = An + LDS_TILE;
            const int koff = (kt + 1) * 64;
            #pragma unroll
            for (int i = 0; i < 4; ++i) {
                async_cp16(A  + offA[i] + koff, An + i*4096 + lds_off);
                async_cp16(Bm + offB[i] + koff, Bn + i*4096 + lds_off);
            }
            // wait only the 8 oldest (current tile); next tile's 8 stay in flight
            asm volatile("s_waitcnt vmcnt(8)" ::: "memory");
        } else {
            asm volatile("s_waitcnt vmcnt(0)" ::: "memory");
        }
        __builtin_amdgcn_s_barrier();
        asm volatile("" ::: "memory");

        // ---- B full (8 x ds_read_b128, swizzled) ----
        bf16x8 b[4][2];
        #pragma unroll
        for (int ni = 0; ni < 4; ++ni) {
            const int row = wn*64 + ni*16 + lrow;
            #pragma unroll
            for (int kk = 0; kk < 2; ++kk) {
                const int ch = ((kk << 2) | quad) ^ swz;
                b[ni][kk] = *reinterpret_cast<const bf16x8*>(&Bs[row*64 + ch*8]);
            }
        }
        // ---- two M-half phases: A-half read + 32 MFMA each ----
        #pragma unroll
        for (int mh = 0; mh < 2; ++mh) {
            bf16x8 a[4][2];
            #pragma unroll
            for (int mi2 = 0; mi2 < 4; ++mi2) {
                const int row = wm*128 + mh*64 + mi2*16 + lrow;
                #pragma unroll
                for (int kk = 0; kk < 2; ++kk) {
                    const int ch = ((kk << 2) | quad) ^ swz;
                    a[mi2][kk] = *reinterpret_cast<const bf16x8*>(&As[row*64 + ch*8]);
                }
            }
            __builtin_amdgcn_s_setprio(1);
            #pragma unroll
            for (int mi2 = 0; mi2 < 4; ++mi2) {
                #pragma unroll
                for (int ni = 0; ni < 4; ++ni) {
                    acc[mh*4+mi2][ni] = __builtin_amdgcn_mfma_f32_16x16x32_bf16(
                        a[mi2][0], b[ni][0], acc[mh*4+mi2][ni], 0, 0, 0);
                    acc[mh*4+mi2][ni] = __builtin_amdgcn_mfma_f32_16x16x32_bf16(
                        a[mi2][1], b[ni][1], acc[mh*4+mi2][ni], 0, 0, 0);
                }
            }
            __builtin_amdgcn_s_setprio(0);
        }

        // all ds_reads of this buffer must have completed before any wave can
        // issue the stage that overwrites it (next iteration)
        asm volatile("s_waitcnt lgkmcnt(0)" ::: "memory");
        __builtin_amdgcn_s_barrier();
        asm volatile("" ::: "memory");
    }

    #pragma unroll
    for (int mi = 0; mi < 8; ++mi) {
        #pragma unroll
        for (int ni = 0; ni < 4; ++ni) {
            #pragma unroll
            for (int reg = 0; reg < 4; ++reg) {
                const int rg = m0 + wm*128 + mi*16 + quad*4 + reg;
                const int cg = n0 + wn*64 + ni*16 + lrow;
                if (rg < MN && cg < MN)
                    W[(size_t)rg * MN + cg] = acc[mi][ni][reg];
            }
        }
    }
}

// ---------------- BatchNorm1d (training-mode batch stats), optional gather ----------------
__global__ void bn_kernel(const float* __restrict__ src, const int* __restrict__ idx,
                          const float* __restrict__ gamma, const float* __restrict__ beta,
                          float* __restrict__ out) {
    const int f = blockIdx.x;       // feature 0..99
    const int b = threadIdx.x;      // 0..127
    __shared__ float red[BATCH];
    const int row = idx ? idx[b] : b;
    const float x = src[row*DE + f];
    red[b] = x; __syncthreads();
    for (int s = 64; s > 0; s >>= 1) { if (b < s) red[b] += red[b + s]; __syncthreads(); }
    const float mu = red[0] * (1.0f/BATCH);
    __syncthreads();
    const float d = x - mu;
    red[b] = d * d; __syncthreads();
    for (int s = 64; s > 0; s >>= 1) { if (b < s) red[b] += red[b + s]; __syncthreads(); }
    const float var = red[0] * (1.0f/BATCH);
    out[b*DE + f] = gamma[f] * d / sqrtf(var + 1e-5f) + beta[f];
}

// ---------------- per-batch factored contraction -> W_out_raw[b][j] ----------------
__global__ void proj_kernel(const float* __restrict__ rb, const float* __restrict__ e1b,
                            const float* __restrict__ e2b,
                            const float* __restrict__ f0, const float* __restrict__ f1,
                            const float* __restrict__ f2, const float* __restrict__ f3,
                            float* __restrict__ wraw) {
    const int b = blockIdx.x, t = threadIdx.x;
    __shared__ float rv[DE], e1v[DE], e2v[DE];
    __shared__ float R0[KDIM], E1[KDIM], E2[KDIM], T[KDIM], S[KDIM];
    if (t < DE) { rv[t] = rb[b*DE+t]; e1v[t] = e1b[b*DE+t]; e2v[t] = e2b[b*DE+t]; }
    __syncthreads();
    // R0[a,be] = sum_p r[p] f0[a,p,be]; E1[be,c] = sum_i e1[i] f1[be,i,c]; E2[d,a] = sum_k e2[k] f3[d,k,a]
    for (int e = t; e < KDIM; e += 256) {
        const int u = e / 40, v = e % 40;
        const int base = u*4000 + v;
        float aR=0.f, aE1=0.f, aE2=0.f;
        for (int p = 0; p < DE; ++p) {
            aR  += rv[p]  * f0[base + p*40];
            aE1 += e1v[p] * f1[base + p*40];
            aE2 += e2v[p] * f3[base + p*40];
        }
        R0[e] = aR; E1[e] = aE1; E2[e] = aE2;
    }
    __syncthreads();
    // T[a,c] = sum_be R0[a,be] E1[be,c]
    for (int e = t; e < KDIM; e += 256) {
        const int a = e / 40, c = e % 40;
        float acc = 0.f;
        #pragma unroll
        for (int y = 0; y < 40; ++y) acc += R0[a*40+y] * E1[y*40+c];
        T[e] = acc;
    }
    __syncthreads();
    // S[c,d] = sum_a T[a,c] E2[d,a]
    for (int e = t; e < KDIM; e += 256) {
        const int c = e / 40, d = e % 40;
        float acc = 0.f;
        #pragma unroll
        for (int y = 0; y < 40; ++y) acc += T[y*40+c] * E2[d*40+y];
        S[e] = acc;
    }
    __syncthreads();
    // wraw[b,j] = sum_{c,d} S[c,d] f2[c,j,d]
    if (t < DE) {
        float acc = 0.f;
        for (int c = 0; c < 40; ++c) {
            #pragma unroll
            for (int d = 0; d < 40; ++d)
                acc += S[c*40+d] * f2[c*4000 + t*40 + d];
        }
        wraw[b*DE + t] = acc;
    }
}

// ---------------- scores: out[b][n] = dot(wbn[b], E[n]) (raw scores into pred region) ----------
__global__ void scores_kernel(const float* __restrict__ wbn, const float* __restrict__ E,
                              float* __restrict__ scores) {
    const int bx = blockIdx.x;
    const int b = bx >> 3, chunk = bx & 7;
    const int t = threadIdx.x;
    __shared__ __align__(16) float wsh[DE];
    if (t < DE) wsh[t] = wbn[b*DE + t];
    __syncthreads();
    const float4* wv = reinterpret_cast<const float4*>(wsh);
    const int n_end = (chunk + 1) * 1250;
    for (int n = chunk*1250 + t; n < n_end; n += 256) {
        const float4* er = reinterpret_cast<const float4*>(E + (size_t)n * DE);
        float acc = 0.f;
        #pragma unroll
        for (int q = 0; q < 25; ++q) {
            const float4 e4 = er[q], w4 = wv[q];
            acc += e4.x*w4.x + e4.y*w4.y + e4.z*w4.z + e4.w*w4.w;
        }
        scores[(size_t)b*NENT + n] = acc;
    }
}

__global__ void softmax_reduce_kernel(const float* __restrict__ scores,
                                      float* __restrict__ rmax, float* __restrict__ rsum) {
    const int b = blockIdx.x, t = threadIdx.x;
    __shared__ float red[256];
    const float* s = scores + (size_t)b*NENT;
    float m = -1e30f;
    for (int n = t; n < NENT; n += 256) m = fmaxf(m, s[n]);
    red[t] = m; __syncthreads();
    for (int st = 128; st > 0; st >>= 1) { if (t < st) red[t] = fmaxf(red[t], red[t+st]); __syncthreads(); }
    m = red[0]; __syncthreads();
    float sum = 0.f;
    for (int n = t; n < NENT; n += 256) sum += expf(s[n] - m);
    red[t] = sum; __syncthreads();
    for (int st = 128; st > 0; st >>= 1) { if (t < st) red[t] += red[t+st]; __syncthreads(); }
    if (t == 0) { rmax[b] = m; rsum[b] = red[0]; }
}

__global__ void pred_kernel(float* __restrict__ out, const float* __restrict__ rmax,
                            const float* __restrict__ rsum) {
    const int i = blockIdx.x*256 + threadIdx.x;
    const int b = i / NENT;
    out[i] = expf(out[i] - rmax[b]) / rsum[b];
}

extern "C" void kernel_launch(void* const* d_in, const int* in_sizes, int n_in,
                              void* d_out, int out_size, void* d_ws, size_t ws_size,
                              hipStream_t stream) {
    (void)in_sizes; (void)n_in; (void)out_size; (void)ws_size;
    const float* E    = (const float*)d_in[0];
    const float* Rw   = (const float*)d_in[1];
    const float* f0   = (const float*)d_in[2];
    const float* f1   = (const float*)d_in[3];
    const float* f2   = (const float*)d_in[4];
    const float* f3   = (const float*)d_in[5];
    const float* bnrg = (const float*)d_in[6];
    const float* bnrb = (const float*)d_in[7];
    const float* bneg = (const float*)d_in[8];
    const float* bneb = (const float*)d_in[9];
    const float* bnwg = (const float*)d_in[10];
    const float* bnwb = (const float*)d_in[11];
    const int* r_idx  = (const int*)d_in[12];
    const int* e_idx1 = (const int*)d_in[13];
    const int* e_idx2 = (const int*)d_in[14];
    // d_in[15] = miss_ent_domain, fixed at 2 for this problem's setup (eq: bijk,bi,bk->bj)

    float* out = (float*)d_out;
    float* Wt  = out + PRED_SIZE;       // W region: 1e8 floats

    char* ws = (char*)d_ws;
    unsigned short* Abf = (unsigned short*)ws;                  // 32 MB
    unsigned short* Bbf = (unsigned short*)(ws + 32000000);     // 32 MB
    float* rbn  = (float*)(ws + 64000000);
    float* e1bn = rbn  + BATCH*DE;
    float* e2bn = e1bn + BATCH*DE;
    float* wraw = e2bn + BATCH*DE;
    float* wbn  = wraw + BATCH*DE;
    float* rmax = wbn  + BATCH*DE;
    float* rsum = rmax + BATCH;

    // allow 128 KiB dynamic LDS for the gemm (one-time, capture-safe)
    static bool s_attr = false;
    if (!s_attr) {
        hipFuncSetAttribute((const void*)gemm_kernel,
                            hipFuncAttributeMaxDynamicSharedMemorySize, 131072);
        s_attr = true;
    }

    prep_A_kernel<<<MN, 256, 0, stream>>>(f0, f1, Abf);
    prep_B_kernel<<<MN, 256, 0, stream>>>(f2, f3, Bbf);
    gemm_kernel<<<1600, 512, 131072, stream>>>(Abf, Bbf, Wt);

    bn_kernel<<<DE, BATCH, 0, stream>>>(Rw, r_idx, bnrg, bnrb, rbn);
    bn_kernel<<<DE, BATCH, 0, stream>>>(E, e_idx1, bneg, bneb, e1bn);
    bn_kernel<<<DE, BATCH, 0, stream>>>(E, e_idx2, bneg, bneb, e2bn);
    proj_kernel<<<BATCH, 256, 0, stream>>>(rbn, e1bn, e2bn, f0, f1, f2, f3, wraw);
    bn_kernel<<<DE, BATCH, 0, stream>>>(wraw, nullptr, bnwg, bnwb, wbn);
    scores_kernel<<<BATCH*8, 256, 0, stream>>>(wbn, E, out);
    softmax_reduce_kernel<<<BATCH, 256, 0, stream>>>(out, rmax, rsum);
    pred_kernel<<<PRED_SIZE/256, 256, 0, stream>>>(out, rmax, rsum);
}